// Round 5
// baseline (90.189 us; speedup 1.0000x reference)
//
#include <hip/hip_runtime.h>
#include <math.h>

// SelfRouting2d — collapsed math:
//   softmax over K of K-identical logits == 1/K exactly -> W2, b2 cancel.
//   out[b,k,u] = (1/S[b]) * sum_i W1[k,u,i] * z[b,i]
//   z[b,i] = sum_n a[b,n]*x[b,i,n],  a[b,n]=||x[b,:,n]||_2,  S[b]=sum_n a[b,n]
//
// Single kernel, no grid.sync: per-b "last block finalizes" pattern.
//   part A (all 1024 blocks): per-(b,chunk) z/s partials; x read from HBM once,
//     float4-coalesced, LDS-staged with XOR quad swizzle (conflict-free).
//   arrival: agent-scope z/s stores + atomicAdd(cnt[b]); 16th arriver finalizes
//     that b (512 outputs) — no spinning anywhere, finalizes overlap part A.
// cnt[] zeroed per replay by a 256B hipMemsetAsync node (graph-capturable).

#define BB 64
#define IN_UNITS 64
#define NCAPS 2048
#define OUT_PER_B 512   // K=32 * U=16
#define CHUNKS 16
#define TILE_N 128

__global__ __launch_bounds__(256, 4) void sr_fused(
    const float* __restrict__ x, const float* __restrict__ W1,
    float* __restrict__ out, float* __restrict__ z_part,
    float* __restrict__ s_part, int* __restrict__ cnt)
{
  __shared__ __align__(16) float xt[IN_UNITS][TILE_N];  // 32KB, swizzled [i][nquad^..]
  __shared__ float4 ssqp[8][32];                        // 4KB per-(ih,q) ssq partials
  __shared__ __align__(16) float a_lds[TILE_N];
  __shared__ float ztmp[4][IN_UNITS];
  __shared__ float swave[2];
  __shared__ __align__(16) float z_l[IN_UNITS];
  __shared__ float sinv_l;
  __shared__ int islast;

  const int bid   = blockIdx.x;
  const int b     = bid >> 4;          // CHUNKS = 16
  const int chunk = bid & 15;
  const int n0    = chunk * TILE_N;
  const int t     = threadIdx.x;

  const int q  = t & 31;               // quad within row (32 quads = 128 floats)
  const int ih = t >> 5;               // owns rows ih*8 .. ih*8+7

  // ---- part A phase 1: coalesced float4 read of the 32KB tile + ssq on the fly
  const float* xb = x + (size_t)b * IN_UNITS * NCAPS + n0;
  float4 ssq4 = make_float4(0.f, 0.f, 0.f, 0.f);
  #pragma unroll
  for (int j = 0; j < 8; ++j) {
    const int r = ih * 8 + j;
    float4 xv = reinterpret_cast<const float4*>(xb + (size_t)r * NCAPS)[q];
    ssq4.x = fmaf(xv.x, xv.x, ssq4.x);
    ssq4.y = fmaf(xv.y, xv.y, ssq4.y);
    ssq4.z = fmaf(xv.z, xv.z, ssq4.z);
    ssq4.w = fmaf(xv.w, xv.w, ssq4.w);
    reinterpret_cast<float4*>(&xt[r][0])[q ^ (r & 7)] = xv;  // XOR swizzle
  }
  ssqp[ih][q] = ssq4;
  __syncthreads();

  // a[n] = sqrt(sum of 8 ih-partials); threads 0..127 own one n each
  float a = 0.f;
  if (t < TILE_N) {
    const int nq = t >> 2, c = t & 3;
    float ss = 0.f;
    #pragma unroll
    for (int k = 0; k < 8; ++k)
      ss += reinterpret_cast<const float*>(&ssqp[k][nq])[c];  // bank = t%32
    a = sqrtf(ss);
    a_lds[t] = a;
  }
  float s = a;
  #pragma unroll
  for (int off = 32; off > 0; off >>= 1) s += __shfl_down(s, off, 64);
  if ((t & 63) == 0 && t < 128) swave[t >> 6] = s;
  __syncthreads();
  if (t == 0) {
    __hip_atomic_store(&s_part[b * CHUNKS + chunk], swave[0] + swave[1],
                       __ATOMIC_RELAXED, __HIP_MEMORY_SCOPE_AGENT);
  }

  // ---- part A phase 2: z partial from LDS (conflict-free via swizzle)
  {
    const int i  = t & 63;
    const int tg = t >> 6;             // owns quads tg*8 .. tg*8+7
    const float4* a4 = reinterpret_cast<const float4*>(a_lds);
    float acc = 0.f;
    #pragma unroll
    for (int m = 0; m < 8; ++m) {
      const int qq = tg * 8 + m;
      float4 xv = reinterpret_cast<const float4*>(&xt[i][0])[qq ^ (i & 7)];
      float4 av = a4[qq];              // uniform addr -> broadcast
      acc = fmaf(xv.x, av.x, acc);
      acc = fmaf(xv.y, av.y, acc);
      acc = fmaf(xv.z, av.z, acc);
      acc = fmaf(xv.w, av.w, acc);
    }
    ztmp[tg][i] = acc;
  }
  __syncthreads();
  if (t < IN_UNITS) {
    float zz = ztmp[0][t] + ztmp[1][t] + ztmp[2][t] + ztmp[3][t];
    __hip_atomic_store(&z_part[((size_t)b * CHUNKS + chunk) * IN_UNITS + t], zz,
                       __ATOMIC_RELAXED, __HIP_MEMORY_SCOPE_AGENT);
  }

  // ---- arrival: 16th chunk-block of this b does the finalize; others exit
  __syncthreads();
  if (t == 0) {
    __threadfence();  // release: make this block's agent stores globally visible
    int old = __hip_atomic_fetch_add(&cnt[b], 1, __ATOMIC_ACQ_REL,
                                     __HIP_MEMORY_SCOPE_AGENT);
    islast = (old == CHUNKS - 1) ? 1 : 0;
  }
  __syncthreads();
  if (!islast) return;
  __threadfence();    // acquire side

  // ---- finalize b: gather 16 z/s partials (agent loads), then 512 outputs
  {
    const int i = t & 63, grp = t >> 6;
    float zz = 0.f;
    #pragma unroll
    for (int c = 0; c < 4; ++c)
      zz += __hip_atomic_load(
          &z_part[((size_t)b * CHUNKS + grp * 4 + c) * IN_UNITS + i],
          __ATOMIC_RELAXED, __HIP_MEMORY_SCOPE_AGENT);
    ztmp[grp][i] = zz;
  }
  if (t == 0) {
    float ss = 0.f;
    #pragma unroll
    for (int c = 0; c < CHUNKS; ++c)
      ss += __hip_atomic_load(&s_part[b * CHUNKS + c],
                              __ATOMIC_RELAXED, __HIP_MEMORY_SCOPE_AGENT);
    sinv_l = 1.0f / ss;
  }
  __syncthreads();
  if (t < IN_UNITS) z_l[t] = ztmp[0][t] + ztmp[1][t] + ztmp[2][t] + ztmp[3][t];
  __syncthreads();

  // 4 threads per output, coalesced W1 (64B lane stride), 8 passes of 64 outputs
  const int part = t & 3;
  const int jl   = t >> 2;
  const float4* z4 = reinterpret_cast<const float4*>(z_l) + part * 4;
  const float4 zv0 = z4[0], zv1 = z4[1], zv2 = z4[2], zv3 = z4[3];
  const float si = sinv_l;
  #pragma unroll
  for (int g = 0; g < 8; ++g) {
    const int j = g * 64 + jl;
    const float4* w4 = reinterpret_cast<const float4*>(
        W1 + (size_t)j * IN_UNITS + part * 16);
    float4 wv0 = w4[0], wv1 = w4[1], wv2 = w4[2], wv3 = w4[3];
    float acc = 0.f;
    acc = fmaf(wv0.x, zv0.x, acc); acc = fmaf(wv0.y, zv0.y, acc);
    acc = fmaf(wv0.z, zv0.z, acc); acc = fmaf(wv0.w, zv0.w, acc);
    acc = fmaf(wv1.x, zv1.x, acc); acc = fmaf(wv1.y, zv1.y, acc);
    acc = fmaf(wv1.z, zv1.z, acc); acc = fmaf(wv1.w, zv1.w, acc);
    acc = fmaf(wv2.x, zv2.x, acc); acc = fmaf(wv2.y, zv2.y, acc);
    acc = fmaf(wv2.z, zv2.z, acc); acc = fmaf(wv2.w, zv2.w, acc);
    acc = fmaf(wv3.x, zv3.x, acc); acc = fmaf(wv3.y, zv3.y, acc);
    acc = fmaf(wv3.z, zv3.z, acc); acc = fmaf(wv3.w, zv3.w, acc);
    acc += __shfl_xor(acc, 1);
    acc += __shfl_xor(acc, 2);
    if (part == 0) out[(size_t)b * OUT_PER_B + j] = acc * si;
  }
}

extern "C" void kernel_launch(void* const* d_in, const int* in_sizes, int n_in,
                              void* d_out, int out_size, void* d_ws, size_t ws_size,
                              hipStream_t stream) {
  const float* x  = (const float*)d_in[0];
  const float* W1 = (const float*)d_in[1];
  // d_in[2] (W2) and d_in[3] (b2) cancel exactly: softmax over the K axis of
  // K-identical logits is uniform 1/K regardless of logit values.
  float* out = (float*)d_out;

  float* z_part = (float*)d_ws;                               // 64*16*64 f32
  float* s_part = z_part + (size_t)BB * CHUNKS * IN_UNITS;    // 64*16 f32
  int*   cnt    = (int*)(s_part + BB * CHUNKS);               // 64 i32

  hipMemsetAsync(cnt, 0, BB * sizeof(int), stream);           // graph memset node
  sr_fused<<<dim3(BB * CHUNKS), dim3(256), 0, stream>>>(x, W1, out,
                                                        z_part, s_part, cnt);
}

// Round 6
// 14.668 us; speedup vs baseline: 6.1485x; 6.1485x over previous
//
#include <hip/hip_runtime.h>
#include <math.h>

// SelfRouting2d — collapsed math:
//   softmax over K of K-identical logits == 1/K exactly -> W2, b2 cancel.
//   out[b,k,u] = (1/S[b]) * sum_i W1[k,u,i] * z[b,i]
//   z[b,i] = sum_n a[b,n]*x[b,i,n],  a[b,n]=||x[b,:,n]||_2,  S[b]=sum_n a[b,n]
//
// R6: two kernels (kernel boundary = the cheap cross-block barrier; fused
// variants with grid.sync / fences cost 50-90us on gfx950 due to per-XCD
// buffer_wbl2 on every device-scope release — measured R4/R5).
// Pass1 at MAX occupancy: TILE_N=64, 2048 blocks, LDS 19.7KB -> 8 blocks/CU
// = 32 waves/CU. All LDS access uniform across banks (analysis inline).

#define BB 64
#define IN_UNITS 64
#define NCAPS 2048
#define OUT_PER_B 512   // K=32 * U=16
#define CHUNKS 32
#define TILE_N 64

__global__ __launch_bounds__(256) void sr_pass1(
    const float* __restrict__ x, float* __restrict__ z_part, float* __restrict__ s_part)
{
  __shared__ __align__(16) float xt[IN_UNITS][TILE_N];  // 16KB, quad-swizzled
  __shared__ float4 ssqp[8][16];                        // 2KB  (g-pair, q) partials
  __shared__ __align__(16) float a_lds[TILE_N];         // 256B
  __shared__ float ztmp[4][IN_UNITS];                   // 1KB
  // total 19.7KB -> 8 blocks/CU, 32 waves/CU (max)

  const int bid   = blockIdx.x;
  const int b     = bid >> 5;          // CHUNKS = 32
  const int chunk = bid & 31;
  const int n0    = chunk * TILE_N;
  const int t     = threadIdx.x;

  const int q = t & 15;                // n-quad within row (16 quads = 64 floats)
  const int g = t >> 4;                // 0..15 -> owns rows g*4 .. g*4+3

  // ---- phase 1: coalesced float4 read of the 16KB tile (4x 256B segments per
  // wave-instr) + ssq on the fly. LDS write quad p=q^(r&15): per row a
  // permutation of 16 quads -> 64 dwords over banks (p*4+c)%32, uniform.
  const float* xb = x + (size_t)b * IN_UNITS * NCAPS + n0;
  float4 ssq4 = make_float4(0.f, 0.f, 0.f, 0.f);
  #pragma unroll
  for (int j = 0; j < 4; ++j) {
    const int r = g * 4 + j;
    float4 xv = reinterpret_cast<const float4*>(xb + (size_t)r * NCAPS)[q];
    ssq4.x = fmaf(xv.x, xv.x, ssq4.x);
    ssq4.y = fmaf(xv.y, xv.y, ssq4.y);
    ssq4.z = fmaf(xv.z, xv.z, ssq4.z);
    ssq4.w = fmaf(xv.w, xv.w, ssq4.w);
    reinterpret_cast<float4*>(&xt[r][0])[q ^ (r & 15)] = xv;  // XOR swizzle
  }
  // pair-reduce g with g^1 (lanes t, t^16 share a wave): ssqp rows halve to 8
  ssq4.x += __shfl_xor(ssq4.x, 16, 64);
  ssq4.y += __shfl_xor(ssq4.y, 16, 64);
  ssq4.z += __shfl_xor(ssq4.z, 16, 64);
  ssq4.w += __shfl_xor(ssq4.w, 16, 64);
  if ((g & 1) == 0) ssqp[g >> 1][q] = ssq4;
  __syncthreads();

  // ---- a[n] + S partial: wave 0 only (t<64 is one full wave)
  if (t < TILE_N) {
    const int nq = t >> 2, c = t & 3;
    float ss = 0.f;
    #pragma unroll
    for (int k = 0; k < 8; ++k) {
      const int kk = (k + (t & 7)) & 7;  // rotate -> dword idx kk*64+t, bank t%32
      ss += reinterpret_cast<const float*>(&ssqp[kk][nq])[c];
    }
    float a = sqrtf(ss);
    a_lds[t] = a;
    float s = a;
    #pragma unroll
    for (int off = 32; off > 0; off >>= 1) s += __shfl_down(s, off, 64);
    if (t == 0) s_part[b * CHUNKS + chunk] = s;
  }
  __syncthreads();

  // ---- phase 2: z partial from LDS. Read quad p=qq^(i&15): 16 quads x 4
  // lanes x 4 dwords = 8 dwords/bank, uniform. a4[qq] wave-uniform broadcast.
  {
    const int i  = t & 63;
    const int tg = t >> 6;             // owns quads tg*4 .. tg*4+3
    const float4* a4 = reinterpret_cast<const float4*>(a_lds);
    float acc = 0.f;
    #pragma unroll
    for (int m = 0; m < 4; ++m) {
      const int qq = tg * 4 + m;
      float4 xv = reinterpret_cast<const float4*>(&xt[i][0])[qq ^ (i & 15)];
      float4 av = a4[qq];
      acc = fmaf(xv.x, av.x, acc);
      acc = fmaf(xv.y, av.y, acc);
      acc = fmaf(xv.z, av.z, acc);
      acc = fmaf(xv.w, av.w, acc);
    }
    ztmp[tg][i] = acc;
  }
  __syncthreads();
  if (t < IN_UNITS) {
    z_part[((size_t)b * CHUNKS + chunk) * IN_UNITS + t] =
        ztmp[0][t] + ztmp[1][t] + ztmp[2][t] + ztmp[3][t];
  }
}

__global__ __launch_bounds__(256) void sr_pass2(
    const float* __restrict__ z_part, const float* __restrict__ s_part,
    const float* __restrict__ W1, float* __restrict__ out)
{
  __shared__ float ztmp[4][IN_UNITS];
  __shared__ __align__(16) float z_l[IN_UNITS];
  const int bid = blockIdx.x;
  const int b   = bid >> 3;            // 8 j-groups per b
  const int g   = bid & 7;
  const int t   = threadIdx.x;

  // coalesced z gather: lanes span i; thread sums 8 of the 32 chunks
  {
    const int i = t & 63, tg = t >> 6;
    float zz = 0.f;
    #pragma unroll
    for (int k = 0; k < 8; ++k)
      zz += z_part[((size_t)b * CHUNKS + tg + 4 * k) * IN_UNITS + i];
    ztmp[tg][i] = zz;
  }
  float ss = 0.f;
  #pragma unroll
  for (int c = 0; c < CHUNKS; ++c) ss += s_part[b * CHUNKS + c];  // uniform -> scalar
  const float sinv = 1.0f / ss;
  __syncthreads();
  if (t < IN_UNITS) z_l[t] = ztmp[0][t] + ztmp[1][t] + ztmp[2][t] + ztmp[3][t];
  __syncthreads();

  // output j = g*64 + (t>>2); 4 threads/output -> W1 reads contiguous 64B
  // lane stride (wave covers 4KB of W1 per pass, fully coalesced).
  const int jl   = t >> 2;
  const int part = t & 3;
  const int j    = g * 64 + jl;
  const float4* w4 = reinterpret_cast<const float4*>(W1 + (size_t)j * IN_UNITS + part * 16);
  const float4* z4 = reinterpret_cast<const float4*>(z_l) + part * 4;
  float acc = 0.f;
  #pragma unroll
  for (int jj = 0; jj < 4; ++jj) {
    float4 wv = w4[jj];
    float4 zv = z4[jj];
    acc = fmaf(wv.x, zv.x, acc);
    acc = fmaf(wv.y, zv.y, acc);
    acc = fmaf(wv.z, zv.z, acc);
    acc = fmaf(wv.w, zv.w, acc);
  }
  acc += __shfl_xor(acc, 1);
  acc += __shfl_xor(acc, 2);
  if (part == 0) out[(size_t)b * OUT_PER_B + j] = acc * sinv;
}

extern "C" void kernel_launch(void* const* d_in, const int* in_sizes, int n_in,
                              void* d_out, int out_size, void* d_ws, size_t ws_size,
                              hipStream_t stream) {
  const float* x  = (const float*)d_in[0];
  const float* W1 = (const float*)d_in[1];
  // d_in[2] (W2) and d_in[3] (b2) cancel exactly: softmax over the K axis of
  // K-identical logits is uniform 1/K regardless of logit values.
  float* out = (float*)d_out;

  float* z_part = (float*)d_ws;                               // 64*32*64 f32 (512KB)
  float* s_part = z_part + (size_t)BB * CHUNKS * IN_UNITS;    // 64*32 f32

  sr_pass1<<<dim3(BB * CHUNKS), dim3(256), 0, stream>>>(x, z_part, s_part);
  sr_pass2<<<dim3(BB * 8), dim3(256), 0, stream>>>(z_part, s_part, W1, out);
}

// Round 7
// 14.244 us; speedup vs baseline: 6.3316x; 1.0298x over previous
//
#include <hip/hip_runtime.h>
#include <math.h>

// SelfRouting2d — collapsed math:
//   softmax over K of K-identical logits == 1/K exactly -> W2, b2 cancel.
//   out[b,k,u] = (1/S[b]) * sum_i W1[k,u,i] * z[b,i]
//   z[b,i] = sum_n a[b,n]*x[b,i,n],  a[b,n]=||x[b,:,n]||_2,  S[b]=sum_n a[b,n]
//
// R7: two kernels (kernel boundary is the cheap cross-block barrier: fused
// grid.sync / fence variants cost 50-90us on gfx950 — measured R4/R5).
// Pass1 keeps the x-tile IN REGISTERS (no LDS round-trip): ssq via
// shfl pair-reduce + tiny LDS finalize; z via 5-round shfl_xor butterfly
// within the 32 lanes sharing a row-group. LDS = 2.4KB, 2 barriers.

#define BB 64
#define IN_UNITS 64
#define NCAPS 2048
#define OUT_PER_B 512   // K=32 * U=16
#define CHUNKS 16
#define TILE_N 128

__global__ __launch_bounds__(256) void sr_pass1(
    const float* __restrict__ x, float* __restrict__ z_part, float* __restrict__ s_part)
{
  __shared__ float4 ssqp[4][32];                 // 2KB: (g-pair, q) ssq partials
  __shared__ __align__(16) float a_lds[TILE_N];  // 512B
  __shared__ float swave[2];

  const int bid   = blockIdx.x;
  const int b     = bid >> 4;          // CHUNKS = 16
  const int chunk = bid & 15;
  const int n0    = chunk * TILE_N;
  const int t     = threadIdx.x;

  const int q = t & 31;                // quad (4 n's) within the 128-float row chunk
  const int g = t >> 5;                // 0..7 -> owns rows g*8 .. g*8+7

  // ---- phase 1: coalesced float4 loads, tile stays in registers
  const float* xb = x + (size_t)b * IN_UNITS * NCAPS + n0;
  float4 xv0, xv1, xv2, xv3, xv4, xv5, xv6, xv7;
  {
    const size_t r0 = (size_t)(g * 8) * NCAPS;
    xv0 = reinterpret_cast<const float4*>(xb + r0)[q];
    xv1 = reinterpret_cast<const float4*>(xb + r0 + NCAPS)[q];
    xv2 = reinterpret_cast<const float4*>(xb + r0 + 2 * NCAPS)[q];
    xv3 = reinterpret_cast<const float4*>(xb + r0 + 3 * NCAPS)[q];
    xv4 = reinterpret_cast<const float4*>(xb + r0 + 4 * NCAPS)[q];
    xv5 = reinterpret_cast<const float4*>(xb + r0 + 5 * NCAPS)[q];
    xv6 = reinterpret_cast<const float4*>(xb + r0 + 6 * NCAPS)[q];
    xv7 = reinterpret_cast<const float4*>(xb + r0 + 7 * NCAPS)[q];
  }
  // ssq over this thread's 8 rows (per n in its quad)
  float4 ssq4;
  ssq4.x = xv0.x * xv0.x; ssq4.y = xv0.y * xv0.y;
  ssq4.z = xv0.z * xv0.z; ssq4.w = xv0.w * xv0.w;
  ssq4.x = fmaf(xv1.x, xv1.x, ssq4.x); ssq4.y = fmaf(xv1.y, xv1.y, ssq4.y);
  ssq4.z = fmaf(xv1.z, xv1.z, ssq4.z); ssq4.w = fmaf(xv1.w, xv1.w, ssq4.w);
  ssq4.x = fmaf(xv2.x, xv2.x, ssq4.x); ssq4.y = fmaf(xv2.y, xv2.y, ssq4.y);
  ssq4.z = fmaf(xv2.z, xv2.z, ssq4.z); ssq4.w = fmaf(xv2.w, xv2.w, ssq4.w);
  ssq4.x = fmaf(xv3.x, xv3.x, ssq4.x); ssq4.y = fmaf(xv3.y, xv3.y, ssq4.y);
  ssq4.z = fmaf(xv3.z, xv3.z, ssq4.z); ssq4.w = fmaf(xv3.w, xv3.w, ssq4.w);
  ssq4.x = fmaf(xv4.x, xv4.x, ssq4.x); ssq4.y = fmaf(xv4.y, xv4.y, ssq4.y);
  ssq4.z = fmaf(xv4.z, xv4.z, ssq4.z); ssq4.w = fmaf(xv4.w, xv4.w, ssq4.w);
  ssq4.x = fmaf(xv5.x, xv5.x, ssq4.x); ssq4.y = fmaf(xv5.y, xv5.y, ssq4.y);
  ssq4.z = fmaf(xv5.z, xv5.z, ssq4.z); ssq4.w = fmaf(xv5.w, xv5.w, ssq4.w);
  ssq4.x = fmaf(xv6.x, xv6.x, ssq4.x); ssq4.y = fmaf(xv6.y, xv6.y, ssq4.y);
  ssq4.z = fmaf(xv6.z, xv6.z, ssq4.z); ssq4.w = fmaf(xv6.w, xv6.w, ssq4.w);
  ssq4.x = fmaf(xv7.x, xv7.x, ssq4.x); ssq4.y = fmaf(xv7.y, xv7.y, ssq4.y);
  ssq4.z = fmaf(xv7.z, xv7.z, ssq4.z); ssq4.w = fmaf(xv7.w, xv7.w, ssq4.w);

  // pair-reduce g with g^1 (lanes t, t^32 in the same wave)
  ssq4.x += __shfl_xor(ssq4.x, 32, 64);
  ssq4.y += __shfl_xor(ssq4.y, 32, 64);
  ssq4.z += __shfl_xor(ssq4.z, 32, 64);
  ssq4.w += __shfl_xor(ssq4.w, 32, 64);
  if ((g & 1) == 0) ssqp[g >> 1][q] = ssq4;   // 4 partials (16 rows each)
  __syncthreads();

  // ---- a[n] = sqrt(sum of 4 partials); threads 0..127 (waves 0,1) own one n
  if (t < TILE_N) {
    const int nq = t >> 2, c = t & 3;
    float ss = 0.f;
    #pragma unroll
    for (int k = 0; k < 4; ++k)
      ss += reinterpret_cast<const float*>(&ssqp[k][nq])[c];  // dword k*128+t: bank t%32
    float a = sqrtf(ss);
    a_lds[t] = a;
    float s = a;
    #pragma unroll
    for (int off = 32; off > 0; off >>= 1) s += __shfl_down(s, off, 64);
    if ((t & 63) == 0) swave[t >> 6] = s;
  }
  __syncthreads();
  if (t == 0) s_part[b * CHUNKS + chunk] = swave[0] + swave[1];

  // ---- phase 2: z in registers. av = a quad (one 16B LDS read, reused x8 rows)
  const float4 av = reinterpret_cast<const float4*>(a_lds)[q];
  float z0, z1, z2, z3, z4, z5, z6, z7;
  z0 = fmaf(xv0.x, av.x, fmaf(xv0.y, av.y, fmaf(xv0.z, av.z, xv0.w * av.w)));
  z1 = fmaf(xv1.x, av.x, fmaf(xv1.y, av.y, fmaf(xv1.z, av.z, xv1.w * av.w)));
  z2 = fmaf(xv2.x, av.x, fmaf(xv2.y, av.y, fmaf(xv2.z, av.z, xv2.w * av.w)));
  z3 = fmaf(xv3.x, av.x, fmaf(xv3.y, av.y, fmaf(xv3.z, av.z, xv3.w * av.w)));
  z4 = fmaf(xv4.x, av.x, fmaf(xv4.y, av.y, fmaf(xv4.z, av.z, xv4.w * av.w)));
  z5 = fmaf(xv5.x, av.x, fmaf(xv5.y, av.y, fmaf(xv5.z, av.z, xv5.w * av.w)));
  z6 = fmaf(xv6.x, av.x, fmaf(xv6.y, av.y, fmaf(xv6.z, av.z, xv6.w * av.w)));
  z7 = fmaf(xv7.x, av.x, fmaf(xv7.y, av.y, fmaf(xv7.z, av.z, xv7.w * av.w)));

  // butterfly over the 32 lanes sharing g (masks < 32 stay in the group)
  #pragma unroll
  for (int m = 1; m < 32; m <<= 1) {
    z0 += __shfl_xor(z0, m, 64);
    z1 += __shfl_xor(z1, m, 64);
    z2 += __shfl_xor(z2, m, 64);
    z3 += __shfl_xor(z3, m, 64);
    z4 += __shfl_xor(z4, m, 64);
    z5 += __shfl_xor(z5, m, 64);
    z6 += __shfl_xor(z6, m, 64);
    z7 += __shfl_xor(z7, m, 64);
  }
  if (q == 0) {  // one lane per row-group writes 8 consecutive rows (2x float4)
    float* zp = z_part + ((size_t)b * CHUNKS + chunk) * IN_UNITS + g * 8;
    reinterpret_cast<float4*>(zp)[0] = make_float4(z0, z1, z2, z3);
    reinterpret_cast<float4*>(zp)[1] = make_float4(z4, z5, z6, z7);
  }
}

__global__ __launch_bounds__(256) void sr_pass2(
    const float* __restrict__ z_part, const float* __restrict__ s_part,
    const float* __restrict__ W1, float* __restrict__ out)
{
  __shared__ float ztmp[4][IN_UNITS];
  __shared__ __align__(16) float z_l[IN_UNITS];
  const int bid = blockIdx.x;
  const int b   = bid >> 3;            // 8 j-groups per b
  const int g   = bid & 7;
  const int t   = threadIdx.x;

  // coalesced z gather: lanes span i; thread-group tg sums 4 of the 16 chunks
  {
    const int i = t & 63, tg = t >> 6;
    float zz = 0.f;
    #pragma unroll
    for (int k = 0; k < 4; ++k)
      zz += z_part[((size_t)b * CHUNKS + tg * 4 + k) * IN_UNITS + i];
    ztmp[tg][i] = zz;
  }
  float ss = 0.f;
  #pragma unroll
  for (int c = 0; c < CHUNKS; ++c) ss += s_part[b * CHUNKS + c];  // uniform -> scalar
  const float sinv = 1.0f / ss;
  __syncthreads();
  if (t < IN_UNITS) z_l[t] = ztmp[0][t] + ztmp[1][t] + ztmp[2][t] + ztmp[3][t];
  __syncthreads();

  // output j = g*64 + (t>>2); 4 threads/output -> W1 reads contiguous 64B
  // lane stride (wave covers 4KB of W1 per pass, fully coalesced).
  const int jl   = t >> 2;
  const int part = t & 3;
  const int j    = g * 64 + jl;
  const float4* w4 = reinterpret_cast<const float4*>(W1 + (size_t)j * IN_UNITS + part * 16);
  const float4* z4 = reinterpret_cast<const float4*>(z_l) + part * 4;
  float acc = 0.f;
  #pragma unroll
  for (int jj = 0; jj < 4; ++jj) {
    float4 wv = w4[jj];
    float4 zv = z4[jj];
    acc = fmaf(wv.x, zv.x, acc);
    acc = fmaf(wv.y, zv.y, acc);
    acc = fmaf(wv.z, zv.z, acc);
    acc = fmaf(wv.w, zv.w, acc);
  }
  acc += __shfl_xor(acc, 1);
  acc += __shfl_xor(acc, 2);
  if (part == 0) out[(size_t)b * OUT_PER_B + j] = acc * sinv;
}

extern "C" void kernel_launch(void* const* d_in, const int* in_sizes, int n_in,
                              void* d_out, int out_size, void* d_ws, size_t ws_size,
                              hipStream_t stream) {
  const float* x  = (const float*)d_in[0];
  const float* W1 = (const float*)d_in[1];
  // d_in[2] (W2) and d_in[3] (b2) cancel exactly: softmax over the K axis of
  // K-identical logits is uniform 1/K regardless of logit values.
  float* out = (float*)d_out;

  float* z_part = (float*)d_ws;                               // 64*16*64 f32
  float* s_part = z_part + (size_t)BB * CHUNKS * IN_UNITS;    // 64*16 f32

  sr_pass1<<<dim3(BB * CHUNKS), dim3(256), 0, stream>>>(x, z_part, s_part);
  sr_pass2<<<dim3(BB * 8), dim3(256), 0, stream>>>(z_part, s_part, W1, out);
}

// Round 8
// 13.252 us; speedup vs baseline: 6.8057x; 1.0749x over previous
//
#include <hip/hip_runtime.h>
#include <math.h>

// SelfRouting2d — collapsed math:
//   softmax over K of K-identical logits == 1/K exactly -> W2, b2 cancel.
//   out[b,k,u] = (1/S[b]) * sum_i W1[k,u,i] * z[b,i]
//   z[b,i] = sum_n a[b,n]*x[b,i,n],  a[b,n]=||x[b,:,n]||_2,  S[b]=sum_n a[b,n]
//
// R8 = R3 structure (best: 13.59us) with 512-thread blocks at the same
// TILE_N=128: LDS 38.6KB -> 4 blocks/CU x 8 waves = 32 waves/CU (max),
// double R3's 16, same tile amortization. Two kernels (fused variants cost
// 50-90us on gfx950: grid.sync spin / per-XCD buffer_wbl2 on fences, R4/R5).

#define BB 64
#define IN_UNITS 64
#define NCAPS 2048
#define OUT_PER_B 512   // K=32 * U=16
#define CHUNKS 16
#define TILE_N 128

__global__ __launch_bounds__(512) void sr_pass1(
    const float* __restrict__ x, float* __restrict__ z_part, float* __restrict__ s_part)
{
  __shared__ __align__(16) float xt[IN_UNITS][TILE_N];  // 32KB, quad-swizzled
  __shared__ float4 ssqp[8][32];                        // 4KB (g-pair, q) partials
  __shared__ __align__(16) float a_lds[TILE_N];         // 512B
  __shared__ float ztmp[8][IN_UNITS];                   // 2KB
  __shared__ float swave[2];
  // total ~38.6KB -> 4 blocks/CU at 512 thr = 32 waves/CU (max)

  const int bid   = blockIdx.x;
  const int b     = bid >> 4;          // CHUNKS = 16
  const int chunk = bid & 15;
  const int n0    = chunk * TILE_N;
  const int t     = threadIdx.x;

  const int q = t & 31;                // quad (4 n's) of the 128-float row chunk
  const int g = t >> 5;                // 0..15 -> owns rows g*4 .. g*4+3

  // ---- phase 1: coalesced float4 read (1KB/wave-instr) + ssq on the fly;
  // stage tile to LDS with XOR quad swizzle (write: 2 rows/wave, 32 perm'd
  // quads each -> every bank x8, the b128 structural minimum).
  const float* xb = x + (size_t)b * IN_UNITS * NCAPS + n0;
  float4 ssq4 = make_float4(0.f, 0.f, 0.f, 0.f);
  #pragma unroll
  for (int j = 0; j < 4; ++j) {
    const int r = g * 4 + j;
    float4 xv = reinterpret_cast<const float4*>(xb + (size_t)r * NCAPS)[q];
    ssq4.x = fmaf(xv.x, xv.x, ssq4.x);
    ssq4.y = fmaf(xv.y, xv.y, ssq4.y);
    ssq4.z = fmaf(xv.z, xv.z, ssq4.z);
    ssq4.w = fmaf(xv.w, xv.w, ssq4.w);
    reinterpret_cast<float4*>(&xt[r][0])[q ^ (r & 7)] = xv;  // XOR swizzle
  }
  // pair-reduce g with g^1 (lanes t, t^32 share a wave) -> 8 partial rows
  ssq4.x += __shfl_xor(ssq4.x, 32, 64);
  ssq4.y += __shfl_xor(ssq4.y, 32, 64);
  ssq4.z += __shfl_xor(ssq4.z, 32, 64);
  ssq4.w += __shfl_xor(ssq4.w, 32, 64);
  if ((g & 1) == 0) ssqp[g >> 1][q] = ssq4;   // 8 partials (8 rows each)
  __syncthreads();

  // ---- a[n] = sqrt(sum of 8 partials); threads 0..127 (waves 0,1) own one n.
  // rotated k-index -> dword idx kk*128 + t -> bank t%32 (2 lanes/bank, free)
  if (t < TILE_N) {
    const int nq = t >> 2, c = t & 3;
    float ss = 0.f;
    #pragma unroll
    for (int k = 0; k < 8; ++k) {
      const int kk = (k + (t & 7)) & 7;
      ss += reinterpret_cast<const float*>(&ssqp[kk][nq])[c];
    }
    float a = sqrtf(ss);
    a_lds[t] = a;
    float s = a;
    #pragma unroll
    for (int off = 32; off > 0; off >>= 1) s += __shfl_down(s, off, 64);
    if ((t & 63) == 0) swave[t >> 6] = s;
  }
  __syncthreads();
  if (t == 0) s_part[b * CHUNKS + chunk] = swave[0] + swave[1];

  // ---- phase 2: z partial from LDS. Per wave tg is constant; read quad
  // p=qq^(i&7) is the conflict-minimal b128 pattern (2 addrs/bank per
  // 16-lane phase). a4[qq] is wave-uniform -> broadcast.
  {
    const int i  = t & 63;
    const int tg = t >> 6;             // 0..7 -> owns quads tg*4 .. tg*4+3
    const float4* a4 = reinterpret_cast<const float4*>(a_lds);
    float acc = 0.f;
    #pragma unroll
    for (int m = 0; m < 4; ++m) {
      const int qq = tg * 4 + m;
      float4 xv = reinterpret_cast<const float4*>(&xt[i][0])[qq ^ (i & 7)];
      float4 av = a4[qq];
      acc = fmaf(xv.x, av.x, acc);
      acc = fmaf(xv.y, av.y, acc);
      acc = fmaf(xv.z, av.z, acc);
      acc = fmaf(xv.w, av.w, acc);
    }
    ztmp[tg][i] = acc;
  }
  __syncthreads();
  if (t < IN_UNITS) {
    float zz = 0.f;
    #pragma unroll
    for (int k = 0; k < 8; ++k) zz += ztmp[k][t];
    z_part[((size_t)b * CHUNKS + chunk) * IN_UNITS + t] = zz;
  }
}

__global__ __launch_bounds__(256) void sr_pass2(
    const float* __restrict__ z_part, const float* __restrict__ s_part,
    const float* __restrict__ W1, float* __restrict__ out)
{
  __shared__ float ztmp[4][IN_UNITS];
  __shared__ __align__(16) float z_l[IN_UNITS];
  const int bid = blockIdx.x;
  const int b   = bid >> 3;            // 8 j-groups per b
  const int g   = bid & 7;
  const int t   = threadIdx.x;

  // coalesced z gather: lanes span i; thread-group tg sums 4 of the 16 chunks
  {
    const int i = t & 63, tg = t >> 6;
    float zz = 0.f;
    #pragma unroll
    for (int k = 0; k < 4; ++k)
      zz += z_part[((size_t)b * CHUNKS + tg * 4 + k) * IN_UNITS + i];
    ztmp[tg][i] = zz;
  }
  float ss = 0.f;
  #pragma unroll
  for (int c = 0; c < CHUNKS; ++c) ss += s_part[b * CHUNKS + c];  // uniform -> scalar
  const float sinv = 1.0f / ss;
  __syncthreads();
  if (t < IN_UNITS) z_l[t] = ztmp[0][t] + ztmp[1][t] + ztmp[2][t] + ztmp[3][t];
  __syncthreads();

  // output j = g*64 + (t>>2); 4 threads/output -> W1 reads contiguous 64B
  // lane stride (wave covers 4KB of W1 per pass, fully coalesced).
  const int jl   = t >> 2;
  const int part = t & 3;
  const int j    = g * 64 + jl;
  const float4* w4 = reinterpret_cast<const float4*>(W1 + (size_t)j * IN_UNITS + part * 16);
  const float4* z4 = reinterpret_cast<const float4*>(z_l) + part * 4;
  float acc = 0.f;
  #pragma unroll
  for (int jj = 0; jj < 4; ++jj) {
    float4 wv = w4[jj];
    float4 zv = z4[jj];
    acc = fmaf(wv.x, zv.x, acc);
    acc = fmaf(wv.y, zv.y, acc);
    acc = fmaf(wv.z, zv.z, acc);
    acc = fmaf(wv.w, zv.w, acc);
  }
  acc += __shfl_xor(acc, 1);
  acc += __shfl_xor(acc, 2);
  if (part == 0) out[(size_t)b * OUT_PER_B + j] = acc * sinv;
}

extern "C" void kernel_launch(void* const* d_in, const int* in_sizes, int n_in,
                              void* d_out, int out_size, void* d_ws, size_t ws_size,
                              hipStream_t stream) {
  const float* x  = (const float*)d_in[0];
  const float* W1 = (const float*)d_in[1];
  // d_in[2] (W2) and d_in[3] (b2) cancel exactly: softmax over the K axis of
  // K-identical logits is uniform 1/K regardless of logit values.
  float* out = (float*)d_out;

  float* z_part = (float*)d_ws;                               // 64*16*64 f32
  float* s_part = z_part + (size_t)BB * CHUNKS * IN_UNITS;    // 64*16 f32

  sr_pass1<<<dim3(BB * CHUNKS), dim3(512), 0, stream>>>(x, z_part, s_part);
  sr_pass2<<<dim3(BB * 8), dim3(256), 0, stream>>>(z_part, s_part, W1, out);
}